// Round 10
// baseline (7763.721 us; speedup 1.0000x reference)
//
#include <hip/hip_runtime.h>
#include <hip/hip_bf16.h>
#include <stdint.h>

#define TOKS 16384
#define HDIM 2048
#define IDIM 1024
#define NEXP 8
#define TOPK 2
#define NPAIR (TOKS*TOPK)   // 32768

typedef __attribute__((ext_vector_type(4))) float f32x4;
typedef __attribute__((ext_vector_type(8))) __bf16 bf16x8;
typedef __attribute__((ext_vector_type(8))) unsigned short u16x8;

#define GLOAD_LDS16(gp, lp) \
  __builtin_amdgcn_global_load_lds((const __attribute__((address_space(1))) void*)(gp), \
                                   (__attribute__((address_space(3))) void*)(lp), 16, 0, 0)

#define LGKM_WAITN(n) asm volatile("s_waitcnt lgkmcnt(" #n ")" ::: "memory")
#define VM_WAITN(n)   asm volatile("s_waitcnt vmcnt(" #n ")" ::: "memory")
#define SBAR0()       __builtin_amdgcn_sched_barrier(0)

__device__ __forceinline__ unsigned short f2bf(float f) {
  unsigned int u = __float_as_uint(f);
  u += 0x7FFF + ((u >> 16) & 1);   // RNE
  return (unsigned short)(u >> 16);
}
__device__ __forceinline__ float bf2f(unsigned short h) {
  return __uint_as_float(((unsigned int)h) << 16);
}

// ---------------- fused conversion: f32 -> bf16 for w13, w2, x ----------------
#define W13_N8 (NEXP * 2 * IDIM * HDIM / 8)   // 4194304
#define W2_N8  (NEXP * HDIM * IDIM / 8)       // 2097152
#define X_N8   (TOKS * HDIM / 8)              // 4194304
__global__ __launch_bounds__(256) void cvt_all(const float* __restrict__ w13,
                                               const float* __restrict__ w2,
                                               const float* __restrict__ x,
                                               unsigned short* __restrict__ w13b,
                                               unsigned short* __restrict__ w2b,
                                               unsigned short* __restrict__ xb) {
  int i = blockIdx.x * 256 + threadIdx.x;
  const float* s; unsigned short* d; int j;
  if (i < W13_N8)              { s = w13; d = w13b; j = i; }
  else if (i < W13_N8 + W2_N8) { s = w2;  d = w2b;  j = i - W13_N8; }
  else                         { s = x;   d = xb;   j = i - W13_N8 - W2_N8; }
  const float4* sp = (const float4*)s + (size_t)j * 2;
  float4 a = sp[0], b = sp[1];
  u16x8 o;
  o[0] = f2bf(a.x); o[1] = f2bf(a.y); o[2] = f2bf(a.z); o[3] = f2bf(a.w);
  o[4] = f2bf(b.x); o[5] = f2bf(b.y); o[6] = f2bf(b.z); o[7] = f2bf(b.w);
  *((u16x8*)d + j) = o;
}

// ---------------- routing ----------------
// ctrl ints: [0..7]=counts [8..15]=offsets [16..23]=cursors [24..31]=rowtile prefix [32]=total tiles
__global__ void route_count(const int* __restrict__ ert, int* __restrict__ ctrl) {
  int p = blockIdx.x * 256 + threadIdx.x;
  if (p < NPAIR) atomicAdd(&ctrl[ert[p]], 1);
}

__global__ void route_scan(int* __restrict__ ctrl) {
  if (blockIdx.x == 0 && threadIdx.x == 0) {
    int off = 0;
    for (int e = 0; e < NEXP; ++e) { ctrl[8 + e] = off; ctrl[16 + e] = off; off += ctrl[e]; }
    int toff = 0;
    for (int e = 0; e < NEXP; ++e) { ctrl[24 + e] = toff; toff += (ctrl[e] + 255) >> 8; }
    ctrl[32] = toff;
  }
}

__global__ void route_scatter(const int* __restrict__ ert, const float* __restrict__ rw,
                              int* __restrict__ ctrl, int* __restrict__ porig,
                              float* __restrict__ pcoef, int* __restrict__ pinv) {
  int p = blockIdx.x * 256 + threadIdx.x;
  if (p < NPAIR) {
    int e = ert[p];
    int pos = atomicAdd(&ctrl[16 + e], 1);
    porig[pos] = p;
    pcoef[pos] = rw[p];
    pinv[p]    = pos;
  }
}

// Shared GEMM machinery: 256x256 tile, BK=32, 2-deep LDS ring (64 KB -> 2
// blocks/CU; inter-block overlap hides the LDS<->MFMA serialization that
// capped 1-block/CU at ~43% MfmaUtil). One-burst register prefetch (round-6
// proven), race-safe ordering: lgkm(0) -> vm(0) -> s_barrier -> STAGE -> RD.
// LDS buf k: A 256x32 bf16 @ (k&1)*32768, B @ +16384. Row = 64B = 4x16B slots,
// slot XOR (row>>1)&3 (source pre-swizzled, same involution).

#define RD_SET(lb, A0v, A1v, B0v, B1v) do {                                          \
  _Pragma("unroll") for (int mi = 0; mi < 4; ++mi) {                                 \
    int r_ = wr * 128 + mi * 16 + l15;                                               \
    A0v[mi] = *(const bf16x8*)((lb) + r_ * 64 + ((l16 ^ ((r_ >> 1) & 3)) << 4)); }   \
  _Pragma("unroll") for (int ni = 0; ni < 2; ++ni) {                                 \
    int nb_ = wc * 64 + ni * 16 + l15;                                               \
    B0v[ni] = *(const bf16x8*)((lb) + 16384 + nb_ * 64 + ((l16 ^ ((nb_ >> 1) & 3)) << 4)); } \
  _Pragma("unroll") for (int ni = 0; ni < 2; ++ni) {                                 \
    int nb_ = wc * 64 + 32 + ni * 16 + l15;                                          \
    B1v[ni] = *(const bf16x8*)((lb) + 16384 + nb_ * 64 + ((l16 ^ ((nb_ >> 1) & 3)) << 4)); } \
  _Pragma("unroll") for (int mi = 0; mi < 4; ++mi) {                                 \
    int r_ = wr * 128 + 64 + mi * 16 + l15;                                          \
    A1v[mi] = *(const bf16x8*)((lb) + r_ * 64 + ((l16 ^ ((r_ >> 1) & 3)) << 4)); }   \
} while (0)

#define MMQ(qm, qn, Av, Bv) do {                                                     \
  __builtin_amdgcn_s_setprio(1);                                                     \
  _Pragma("unroll") for (int mi = 0; mi < 4; ++mi)                                   \
    _Pragma("unroll") for (int ni = 0; ni < 2; ++ni)                                 \
      acc[qm][qn][mi][ni] = __builtin_amdgcn_mfma_f32_16x16x32_bf16(                 \
          Av[mi], Bv[ni], acc[qm][qn][mi][ni], 0, 0, 0);                             \
  __builtin_amdgcn_s_setprio(0);                                                     \
} while (0)

// lgkm ledger (one-burst RD_SET issue order: A0(4), B0(2), B1(2), A1(4)):
//   pending 12 at iter top -> LGKM(6) retires A0+B0 (q0), LGKM(4) retires B1
//   (q1), LGKM(0) retires A1 (q2).  q3 operands already proven.
// vm ledger (ring-2, 4 gloads/tile): at mid-iter, outstanding = tile i+1 only
//   -> VM(0) retires it; barrier then makes cross-wave writes visible before
//   RD_SET(buf i+1), and (with lgkm(0) before each wave's barrier) proves all
//   reads of buf i&1 retired before STAGE(i+2) overwrites it.
#define ITER(i, cA0, cA1, cB0, cB1, nA0, nA1, nB0, nB1) do {                         \
  LGKM_WAITN(6);                                                                     \
  MMQ(0, 0, cA0, cB0);                                                               \
  LGKM_WAITN(4);                                                                     \
  MMQ(0, 1, cA0, cB1);                                                               \
  LGKM_WAITN(0);                                                                     \
  MMQ(1, 0, cA1, cB0);                                                               \
  if ((i) < NT - 1) {                                                                \
    VM_WAITN(0);                                                                     \
    __builtin_amdgcn_s_barrier();                                                    \
    SBAR0();                                                                         \
    if ((i) + 2 < NT) STAGE((i) + 2);                                                \
    RD_SET(lds + (((i) + 1) & 1) * 32768, nA0, nA1, nB0, nB1);                       \
    SBAR0();                                                                         \
  }                                                                                  \
  MMQ(1, 1, cA1, cB1);                                                               \
} while (0)

// XCD-co-located block map: the 8 cb-blocks of one tile occupy 8 consecutive
// dispatch slots of the SAME XCD (bid = x + 8*(tg*8+cb), tile = tg*8+x).
#define TILE_MAP()                                                                   \
  const int x_ = bid & 7, k_ = bid >> 3;                                             \
  const int cb = k_ & 7;                                                             \
  const int tile = ((k_ >> 3) << 3) + x_;

// ============ GEMM1: act = silu(x@Wg^T)*(x@Wu^T) ============
__global__ __launch_bounds__(512, 4) void gemm1(const unsigned short* __restrict__ xb,
                                                const unsigned short* __restrict__ w13b,
                                                const int* __restrict__ ctrl,
                                                const int* __restrict__ porig,
                                                unsigned short* __restrict__ actb) {
  __shared__ __align__(16) char lds[65536];
  const int bid  = blockIdx.x;
  TILE_MAP();
  if (tile >= ctrl[32]) return;
  int e = 7;
  #pragma unroll
  for (int k = 7; k >= 1; --k) if (tile < ctrl[24 + k]) e = k - 1;
  const int rb   = tile - ctrl[24 + e];
  const int Ne   = ctrl[e];
  const int base = ctrl[8 + e];
  const int row0 = rb * 256;
  const int c0   = cb * 128;
  const int tid  = threadIdx.x;
  const int wid  = tid >> 6;
  const int lane = tid & 63;
  const int wr   = wid >> 2;
  const int wc   = wid & 3;
  const int l15  = lane & 15;
  const int l16  = lane >> 4;
  const int NT   = HDIM / 32;   // 64

  // staging pointers (source pre-swizzled): per gload g, row = g*128+wid*16+(lane>>2)
  const unsigned short *gA0, *gA1, *gB0, *gB1;
  {
    int rl = wid * 16 + (lane >> 2);
    int r0 = rl, r1 = 128 + rl;
    int c80 = (lane & 3) ^ ((r0 >> 1) & 3);
    int c81 = (lane & 3) ^ ((r1 >> 1) & 3);
    int rr0 = row0 + r0; if (rr0 > Ne - 1) rr0 = Ne - 1;
    int rr1 = row0 + r1; if (rr1 > Ne - 1) rr1 = Ne - 1;
    gA0 = xb + (size_t)(porig[base + rr0] >> 1) * HDIM + c80 * 8;
    gA1 = xb + (size_t)(porig[base + rr1] >> 1) * HDIM + c81 * 8;
    // B rows: gate/up interleave: nb&32 -> up half; act col = c0 + (nb>>6)*32 + (nb&31)
    int g0 = ((r0 & 32) ? IDIM : 0) + c0 + ((r0 >> 6) << 5) + (r0 & 31);
    int g1 = ((r1 & 32) ? IDIM : 0) + c0 + ((r1 >> 6) << 5) + (r1 & 31);
    gB0 = w13b + ((size_t)e * (2 * IDIM) + g0) * HDIM + c80 * 8;
    gB1 = w13b + ((size_t)e * (2 * IDIM) + g1) * HDIM + c81 * 8;
  }

  f32x4 acc[2][2][4][2];
  #pragma unroll
  for (int qm = 0; qm < 2; ++qm)
    #pragma unroll
    for (int qn = 0; qn < 2; ++qn)
      #pragma unroll
      for (int mi = 0; mi < 4; ++mi)
        #pragma unroll
        for (int ni = 0; ni < 2; ++ni) acc[qm][qn][mi][ni] = (f32x4)(0.0f);

  auto STAGE = [&](int kt) {
    char* d = lds + (kt & 1) * 32768 + wid * 1024;
    GLOAD_LDS16(gA0 + kt * 32, d);
    GLOAD_LDS16(gA1 + kt * 32, d + 8192);
    GLOAD_LDS16(gB0 + kt * 32, d + 16384);
    GLOAD_LDS16(gB1 + kt * 32, d + 24576);
  };

  bf16x8 A0a[4], A1a[4], B0a[2], B1a[2];
  bf16x8 A0b[4], A1b[4], B0b[2], B1b[2];

  STAGE(0); STAGE(1);
  VM_WAITN(4);
  __builtin_amdgcn_s_barrier();
  SBAR0();
  RD_SET(lds, A0a, A1a, B0a, B1a);
  SBAR0();

  for (int i = 0; i < NT; i += 2) {
    ITER(i,     A0a, A1a, B0a, B1a, A0b, A1b, B0b, B1b);
    ITER(i + 1, A0b, A1b, B0b, B1b, A0a, A1a, B0a, B1a);
  }

  // epilogue: silu(gate)*up -> bf16 act (qn=0 gate, qn=1 up)
  #pragma unroll
  for (int qm = 0; qm < 2; ++qm)
    #pragma unroll
    for (int mi = 0; mi < 4; ++mi)
      #pragma unroll
      for (int jj = 0; jj < 4; ++jj) {
        int r = wr * 128 + qm * 64 + mi * 16 + l16 * 4 + jj;
        int rr = row0 + r;
        if (rr < Ne) {
          #pragma unroll
          for (int ni = 0; ni < 2; ++ni) {
            float g = acc[qm][0][mi][ni][jj];
            float u = acc[qm][1][mi][ni][jj];
            float a = g / (1.0f + __expf(-g)) * u;
            actb[(size_t)(base + rr) * IDIM + (c0 + wc * 32 + ni * 16 + l15)] = f2bf(a);
          }
        }
      }
}

// ============ GEMM2: yb[pos] = coef * (act @ w2^T), contiguous stores ============
__global__ __launch_bounds__(512, 4) void gemm2(const unsigned short* __restrict__ actb,
                                                const unsigned short* __restrict__ w2b,
                                                const int* __restrict__ ctrl,
                                                const float* __restrict__ pcoef,
                                                unsigned short* __restrict__ yb) {
  __shared__ __align__(16) char lds[65536];
  const int bid  = blockIdx.x;
  TILE_MAP();
  if (tile >= ctrl[32]) return;
  int e = 7;
  #pragma unroll
  for (int k = 7; k >= 1; --k) if (tile < ctrl[24 + k]) e = k - 1;
  const int rb   = tile - ctrl[24 + e];
  const int Ne   = ctrl[e];
  const int base = ctrl[8 + e];
  const int row0 = rb * 256;
  const int n0   = cb * 256;
  const int tid  = threadIdx.x;
  const int wid  = tid >> 6;
  const int lane = tid & 63;
  const int wr   = wid >> 2;
  const int wc   = wid & 3;
  const int l15  = lane & 15;
  const int l16  = lane >> 4;
  const int NT   = IDIM / 32;   // 32

  const unsigned short *gA0, *gA1, *gB0, *gB1;
  {
    int rl = wid * 16 + (lane >> 2);
    int r0 = rl, r1 = 128 + rl;
    int c80 = (lane & 3) ^ ((r0 >> 1) & 3);
    int c81 = (lane & 3) ^ ((r1 >> 1) & 3);
    int rr0 = row0 + r0; if (rr0 > Ne - 1) rr0 = Ne - 1;
    int rr1 = row0 + r1; if (rr1 > Ne - 1) rr1 = Ne - 1;
    gA0 = actb + (size_t)(base + rr0) * IDIM + c80 * 8;
    gA1 = actb + (size_t)(base + rr1) * IDIM + c81 * 8;
    gB0 = w2b + ((size_t)e * HDIM + n0 + r0) * IDIM + c80 * 8;
    gB1 = w2b + ((size_t)e * HDIM + n0 + r1) * IDIM + c81 * 8;
  }

  f32x4 acc[2][2][4][2];
  #pragma unroll
  for (int qm = 0; qm < 2; ++qm)
    #pragma unroll
    for (int qn = 0; qn < 2; ++qn)
      #pragma unroll
      for (int mi = 0; mi < 4; ++mi)
        #pragma unroll
        for (int ni = 0; ni < 2; ++ni) acc[qm][qn][mi][ni] = (f32x4)(0.0f);

  auto STAGE = [&](int kt) {
    char* d = lds + (kt & 1) * 32768 + wid * 1024;
    GLOAD_LDS16(gA0 + kt * 32, d);
    GLOAD_LDS16(gA1 + kt * 32, d + 8192);
    GLOAD_LDS16(gB0 + kt * 32, d + 16384);
    GLOAD_LDS16(gB1 + kt * 32, d + 24576);
  };

  bf16x8 A0a[4], A1a[4], B0a[2], B1a[2];
  bf16x8 A0b[4], A1b[4], B0b[2], B1b[2];

  STAGE(0); STAGE(1);
  VM_WAITN(4);
  __builtin_amdgcn_s_barrier();
  SBAR0();
  RD_SET(lds, A0a, A1a, B0a, B1a);
  SBAR0();

  for (int i = 0; i < NT; i += 2) {
    ITER(i,     A0a, A1a, B0a, B1a, A0b, A1b, B0b, B1b);
    ITER(i + 1, A0b, A1b, B0b, B1b, A0a, A1a, B0a, B1a);
  }

  // epilogue: contiguous bf16 stores at sorted position, scaled by router coef
  #pragma unroll
  for (int qm = 0; qm < 2; ++qm)
    #pragma unroll
    for (int mi = 0; mi < 4; ++mi)
      #pragma unroll
      for (int jj = 0; jj < 4; ++jj) {
        int r = wr * 128 + qm * 64 + mi * 16 + l16 * 4 + jj;
        int rr = row0 + r;
        if (rr < Ne) {
          float cf = pcoef[base + rr];
          #pragma unroll
          for (int qn = 0; qn < 2; ++qn)
            #pragma unroll
            for (int ni = 0; ni < 2; ++ni) {
              int col = n0 + wc * 64 + qn * 32 + ni * 16 + l15;
              yb[(size_t)(base + rr) * HDIM + col] = f2bf(acc[qm][qn][mi][ni][jj] * cf);
            }
        }
      }
}

// ---------------- reduce: out[t] = yb[pinv[2t]] + yb[pinv[2t+1]] ----------------
__global__ __launch_bounds__(256) void reduce2(const unsigned short* __restrict__ yb,
                                               const int* __restrict__ pinv,
                                               float* __restrict__ out) {
  int i = blockIdx.x * 256 + threadIdx.x;
  int t = i >> 8;                                   // 256 thread-groups of 8 cols
  int g = i & 255;
  int p0 = pinv[2 * t], p1 = pinv[2 * t + 1];
  u16x8 a = *((const u16x8*)(yb + (size_t)p0 * HDIM) + g);
  u16x8 b = *((const u16x8*)(yb + (size_t)p1 * HDIM) + g);
  float4 o0, o1;
  o0.x = bf2f(a[0]) + bf2f(b[0]); o0.y = bf2f(a[1]) + bf2f(b[1]);
  o0.z = bf2f(a[2]) + bf2f(b[2]); o0.w = bf2f(a[3]) + bf2f(b[3]);
  o1.x = bf2f(a[4]) + bf2f(b[4]); o1.y = bf2f(a[5]) + bf2f(b[5]);
  o1.z = bf2f(a[6]) + bf2f(b[6]); o1.w = bf2f(a[7]) + bf2f(b[7]);
  float4* dst = (float4*)(out + (size_t)t * HDIM) + g * 2;
  dst[0] = o0; dst[1] = o1;
}

// ---------------- launcher ----------------
extern "C" void kernel_launch(void* const* d_in, const int* in_sizes, int n_in,
                              void* d_out, int out_size, void* d_ws, size_t ws_size,
                              hipStream_t stream) {
  const float* x   = (const float*)d_in[0];
  const int*   ert = (const int*)d_in[1];
  const float* rw  = (const float*)d_in[2];
  const float* w13 = (const float*)d_in[3];
  const float* w2  = (const float*)d_in[4];
  float* out = (float*)d_out;

  char* ws = (char*)d_ws;
  size_t off = 0;
  auto alloc = [&](size_t bytes) { char* p = ws + off; off += (bytes + 255) & ~255ULL; return p; };
  int*            ctrl  = (int*)           alloc(256);
  int*            porig = (int*)           alloc((size_t)NPAIR * 4);
  float*          pcoef = (float*)         alloc((size_t)NPAIR * 4);
  int*            pinv  = (int*)           alloc((size_t)NPAIR * 4);
  unsigned short* w2b   = (unsigned short*)alloc((size_t)NEXP * HDIM * IDIM * 2);
  unsigned short* actb  = (unsigned short*)alloc((size_t)NPAIR * IDIM * 2);
  unsigned short* w13b  = (unsigned short*)alloc((size_t)NEXP * 2 * IDIM * HDIM * 2);
  unsigned short* xb    = (unsigned short*)alloc((size_t)TOKS * HDIM * 2);
  // yb (NPAIR x HDIM bf16 = 128 MiB) overlays w13b (dead after gemm1)
  unsigned short* yb    = w13b;

  hipMemsetAsync(ctrl, 0, 256, stream);

  cvt_all<<<(W13_N8 + W2_N8 + X_N8) / 256, 256, 0, stream>>>(w13, w2, x, w13b, w2b, xb);

  route_count  <<<NPAIR / 256, 256, 0, stream>>>(ert, ctrl);
  route_scan   <<<1, 64, 0, stream>>>(ctrl);
  route_scatter<<<NPAIR / 256, 256, 0, stream>>>(ert, rw, ctrl, porig, pcoef, pinv);

  gemm1<<<136 * 8, 512, 0, stream>>>(xb, w13b, ctrl, porig, actb);
  gemm2<<<136 * 8, 512, 0, stream>>>(actb, w2b, ctrl, pcoef, yb);
  reduce2<<<(TOKS * HDIM / 8) / 256, 256, 0, stream>>>(yb, pinv, out);
}

// Round 11
// 863.673 us; speedup vs baseline: 8.9892x; 8.9892x over previous
//
#include <hip/hip_runtime.h>
#include <hip/hip_bf16.h>
#include <stdint.h>

#define TOKS 16384
#define HDIM 2048
#define IDIM 1024
#define NEXP 8
#define TOPK 2
#define NPAIR (TOKS*TOPK)   // 32768

typedef __attribute__((ext_vector_type(4))) float f32x4;
typedef __attribute__((ext_vector_type(8))) __bf16 bf16x8;
typedef __attribute__((ext_vector_type(8))) unsigned short u16x8;

#define GLOAD_LDS16(gp, lp) \
  __builtin_amdgcn_global_load_lds((const __attribute__((address_space(1))) void*)(gp), \
                                   (__attribute__((address_space(3))) void*)(lp), 16, 0, 0)

#define LGKM_WAITN(n) asm volatile("s_waitcnt lgkmcnt(" #n ")" ::: "memory")
#define VM_WAITN(n)   asm volatile("s_waitcnt vmcnt(" #n ")" ::: "memory")
#define SBAR0()       __builtin_amdgcn_sched_barrier(0)

__device__ __forceinline__ unsigned short f2bf(float f) {
  unsigned int u = __float_as_uint(f);
  u += 0x7FFF + ((u >> 16) & 1);   // RNE
  return (unsigned short)(u >> 16);
}
__device__ __forceinline__ float bf2f(unsigned short h) {
  return __uint_as_float(((unsigned int)h) << 16);
}

// ---------------- fused conversion: f32 -> bf16 for w13, w2, x ----------------
#define W13_N8 (NEXP * 2 * IDIM * HDIM / 8)   // 4194304
#define W2_N8  (NEXP * HDIM * IDIM / 8)       // 2097152
#define X_N8   (TOKS * HDIM / 8)              // 4194304
__global__ __launch_bounds__(256) void cvt_all(const float* __restrict__ w13,
                                               const float* __restrict__ w2,
                                               const float* __restrict__ x,
                                               unsigned short* __restrict__ w13b,
                                               unsigned short* __restrict__ w2b,
                                               unsigned short* __restrict__ xb) {
  int i = blockIdx.x * 256 + threadIdx.x;
  const float* s; unsigned short* d; int j;
  if (i < W13_N8)              { s = w13; d = w13b; j = i; }
  else if (i < W13_N8 + W2_N8) { s = w2;  d = w2b;  j = i - W13_N8; }
  else                         { s = x;   d = xb;   j = i - W13_N8 - W2_N8; }
  const float4* sp = (const float4*)s + (size_t)j * 2;
  float4 a = sp[0], b = sp[1];
  u16x8 o;
  o[0] = f2bf(a.x); o[1] = f2bf(a.y); o[2] = f2bf(a.z); o[3] = f2bf(a.w);
  o[4] = f2bf(b.x); o[5] = f2bf(b.y); o[6] = f2bf(b.z); o[7] = f2bf(b.w);
  *((u16x8*)d + j) = o;
}

// ---------------- routing ----------------
// ctrl ints: [0..7]=counts [8..15]=offsets [16..23]=cursors [24..31]=rowtile prefix [32]=total tiles
__global__ void route_count(const int* __restrict__ ert, int* __restrict__ ctrl) {
  int p = blockIdx.x * 256 + threadIdx.x;
  if (p < NPAIR) atomicAdd(&ctrl[ert[p]], 1);
}

__global__ void route_scan(int* __restrict__ ctrl) {
  if (blockIdx.x == 0 && threadIdx.x == 0) {
    int off = 0;
    for (int e = 0; e < NEXP; ++e) { ctrl[8 + e] = off; ctrl[16 + e] = off; off += ctrl[e]; }
    int toff = 0;
    for (int e = 0; e < NEXP; ++e) { ctrl[24 + e] = toff; toff += (ctrl[e] + 255) >> 8; }
    ctrl[32] = toff;
  }
}

__global__ void route_scatter(const int* __restrict__ ert, const float* __restrict__ rw,
                              int* __restrict__ ctrl, int* __restrict__ porig,
                              float* __restrict__ pcoef, int* __restrict__ pinv) {
  int p = blockIdx.x * 256 + threadIdx.x;
  if (p < NPAIR) {
    int e = ert[p];
    int pos = atomicAdd(&ctrl[16 + e], 1);
    porig[pos] = p;
    pcoef[pos] = rw[p];
    pinv[p]    = pos;
  }
}

// Shared GEMM machinery: 256x256 tile, BK=32, 2-deep LDS ring (64 KB -> 2
// blocks/CU when VGPR <= 128; inter-block overlap hides the LDS<->MFMA
// serialization that capped 1-block/CU at ~43% MfmaUtil). One-burst register
// prefetch, race-safe ordering: lgkm(0) -> vm(0) -> s_barrier -> STAGE -> RD.
// NOTE: __launch_bounds__(512,2) — NOT (512,4): round-10 showed (512,4) makes
// hipcc clamp to 64 VGPR and spill the whole accumulator (21 GB scratch).
// LDS buf k: A 256x32 bf16 @ (k&1)*32768, B @ +16384. Row = 64B = 4x16B slots,
// slot XOR (row>>1)&3 (source pre-swizzled, same involution).

#define RD_SET(lb, A0v, A1v, B0v, B1v) do {                                          \
  _Pragma("unroll") for (int mi = 0; mi < 4; ++mi) {                                 \
    int r_ = wr * 128 + mi * 16 + l15;                                               \
    A0v[mi] = *(const bf16x8*)((lb) + r_ * 64 + ((l16 ^ ((r_ >> 1) & 3)) << 4)); }   \
  _Pragma("unroll") for (int ni = 0; ni < 2; ++ni) {                                 \
    int nb_ = wc * 64 + ni * 16 + l15;                                               \
    B0v[ni] = *(const bf16x8*)((lb) + 16384 + nb_ * 64 + ((l16 ^ ((nb_ >> 1) & 3)) << 4)); } \
  _Pragma("unroll") for (int ni = 0; ni < 2; ++ni) {                                 \
    int nb_ = wc * 64 + 32 + ni * 16 + l15;                                          \
    B1v[ni] = *(const bf16x8*)((lb) + 16384 + nb_ * 64 + ((l16 ^ ((nb_ >> 1) & 3)) << 4)); } \
  _Pragma("unroll") for (int mi = 0; mi < 4; ++mi) {                                 \
    int r_ = wr * 128 + 64 + mi * 16 + l15;                                          \
    A1v[mi] = *(const bf16x8*)((lb) + r_ * 64 + ((l16 ^ ((r_ >> 1) & 3)) << 4)); }   \
} while (0)

#define MMQ(qm, qn, Av, Bv) do {                                                     \
  __builtin_amdgcn_s_setprio(1);                                                     \
  _Pragma("unroll") for (int mi = 0; mi < 4; ++mi)                                   \
    _Pragma("unroll") for (int ni = 0; ni < 2; ++ni)                                 \
      acc[qm][qn][mi][ni] = __builtin_amdgcn_mfma_f32_16x16x32_bf16(                 \
          Av[mi], Bv[ni], acc[qm][qn][mi][ni], 0, 0, 0);                             \
  __builtin_amdgcn_s_setprio(0);                                                     \
} while (0)

// lgkm ledger (one-burst RD_SET issue order: A0(4), B0(2), B1(2), A1(4)):
//   pending 12 at iter top -> LGKM(6) retires A0+B0 (q0), LGKM(4) retires B1
//   (q1), LGKM(0) retires A1 (q2).  q3 operands already proven.
// vm ledger (ring-2, 4 gloads/tile): at mid-iter, outstanding = tile i+1 only
//   -> VM(0) retires it; barrier then makes cross-wave writes visible before
//   RD_SET(buf i+1), and (with lgkm(0) before each wave's barrier) proves all
//   reads of buf i&1 retired before STAGE(i+2) overwrites it.
#define ITER(i, cA0, cA1, cB0, cB1, nA0, nA1, nB0, nB1) do {                         \
  LGKM_WAITN(6);                                                                     \
  MMQ(0, 0, cA0, cB0);                                                               \
  LGKM_WAITN(4);                                                                     \
  MMQ(0, 1, cA0, cB1);                                                               \
  LGKM_WAITN(0);                                                                     \
  MMQ(1, 0, cA1, cB0);                                                               \
  if ((i) < NT - 1) {                                                                \
    VM_WAITN(0);                                                                     \
    __builtin_amdgcn_s_barrier();                                                    \
    SBAR0();                                                                         \
    if ((i) + 2 < NT) STAGE((i) + 2);                                                \
    RD_SET(lds + (((i) + 1) & 1) * 32768, nA0, nA1, nB0, nB1);                       \
    SBAR0();                                                                         \
  }                                                                                  \
  MMQ(1, 1, cA1, cB1);                                                               \
} while (0)

// XCD-co-located block map: the 8 cb-blocks of one tile occupy 8 consecutive
// dispatch slots of the SAME XCD (bid = x + 8*(tg*8+cb), tile = tg*8+x).
#define TILE_MAP()                                                                   \
  const int x_ = bid & 7, k_ = bid >> 3;                                             \
  const int cb = k_ & 7;                                                             \
  const int tile = ((k_ >> 3) << 3) + x_;

// ============ GEMM1: act = silu(x@Wg^T)*(x@Wu^T) ============
__global__ __launch_bounds__(512, 2) void gemm1(const unsigned short* __restrict__ xb,
                                                const unsigned short* __restrict__ w13b,
                                                const int* __restrict__ ctrl,
                                                const int* __restrict__ porig,
                                                unsigned short* __restrict__ actb) {
  __shared__ __align__(16) char lds[65536];
  const int bid  = blockIdx.x;
  TILE_MAP();
  if (tile >= ctrl[32]) return;
  int e = 7;
  #pragma unroll
  for (int k = 7; k >= 1; --k) if (tile < ctrl[24 + k]) e = k - 1;
  const int rb   = tile - ctrl[24 + e];
  const int Ne   = ctrl[e];
  const int base = ctrl[8 + e];
  const int row0 = rb * 256;
  const int c0   = cb * 128;
  const int tid  = threadIdx.x;
  const int wid  = tid >> 6;
  const int lane = tid & 63;
  const int wr   = wid >> 2;
  const int wc   = wid & 3;
  const int l15  = lane & 15;
  const int l16  = lane >> 4;
  const int NT   = HDIM / 32;   // 64

  // staging pointers (source pre-swizzled): per gload g, row = g*128+wid*16+(lane>>2)
  const unsigned short *gA0, *gA1, *gB0, *gB1;
  {
    int rl = wid * 16 + (lane >> 2);
    int r0 = rl, r1 = 128 + rl;
    int c80 = (lane & 3) ^ ((r0 >> 1) & 3);
    int c81 = (lane & 3) ^ ((r1 >> 1) & 3);
    int rr0 = row0 + r0; if (rr0 > Ne - 1) rr0 = Ne - 1;
    int rr1 = row0 + r1; if (rr1 > Ne - 1) rr1 = Ne - 1;
    gA0 = xb + (size_t)(porig[base + rr0] >> 1) * HDIM + c80 * 8;
    gA1 = xb + (size_t)(porig[base + rr1] >> 1) * HDIM + c81 * 8;
    // B rows: gate/up interleave: nb&32 -> up half; act col = c0 + (nb>>6)*32 + (nb&31)
    int g0 = ((r0 & 32) ? IDIM : 0) + c0 + ((r0 >> 6) << 5) + (r0 & 31);
    int g1 = ((r1 & 32) ? IDIM : 0) + c0 + ((r1 >> 6) << 5) + (r1 & 31);
    gB0 = w13b + ((size_t)e * (2 * IDIM) + g0) * HDIM + c80 * 8;
    gB1 = w13b + ((size_t)e * (2 * IDIM) + g1) * HDIM + c81 * 8;
  }

  f32x4 acc[2][2][4][2];
  #pragma unroll
  for (int qm = 0; qm < 2; ++qm)
    #pragma unroll
    for (int qn = 0; qn < 2; ++qn)
      #pragma unroll
      for (int mi = 0; mi < 4; ++mi)
        #pragma unroll
        for (int ni = 0; ni < 2; ++ni) acc[qm][qn][mi][ni] = (f32x4)(0.0f);

  auto STAGE = [&](int kt) {
    char* d = lds + (kt & 1) * 32768 + wid * 1024;
    GLOAD_LDS16(gA0 + kt * 32, d);
    GLOAD_LDS16(gA1 + kt * 32, d + 8192);
    GLOAD_LDS16(gB0 + kt * 32, d + 16384);
    GLOAD_LDS16(gB1 + kt * 32, d + 24576);
  };

  bf16x8 A0a[4], A1a[4], B0a[2], B1a[2];
  bf16x8 A0b[4], A1b[4], B0b[2], B1b[2];

  STAGE(0); STAGE(1);
  VM_WAITN(4);
  __builtin_amdgcn_s_barrier();
  SBAR0();
  RD_SET(lds, A0a, A1a, B0a, B1a);
  SBAR0();

  for (int i = 0; i < NT; i += 2) {
    ITER(i,     A0a, A1a, B0a, B1a, A0b, A1b, B0b, B1b);
    ITER(i + 1, A0b, A1b, B0b, B1b, A0a, A1a, B0a, B1a);
  }

  // epilogue: silu(gate)*up -> bf16 act (qn=0 gate, qn=1 up)
  #pragma unroll
  for (int qm = 0; qm < 2; ++qm)
    #pragma unroll
    for (int mi = 0; mi < 4; ++mi)
      #pragma unroll
      for (int jj = 0; jj < 4; ++jj) {
        int r = wr * 128 + qm * 64 + mi * 16 + l16 * 4 + jj;
        int rr = row0 + r;
        if (rr < Ne) {
          #pragma unroll
          for (int ni = 0; ni < 2; ++ni) {
            float g = acc[qm][0][mi][ni][jj];
            float u = acc[qm][1][mi][ni][jj];
            float a = g / (1.0f + __expf(-g)) * u;
            actb[(size_t)(base + rr) * IDIM + (c0 + wc * 32 + ni * 16 + l15)] = f2bf(a);
          }
        }
      }
}

// ============ GEMM2: yb[pos] = coef * (act @ w2^T), contiguous stores ============
__global__ __launch_bounds__(512, 2) void gemm2(const unsigned short* __restrict__ actb,
                                                const unsigned short* __restrict__ w2b,
                                                const int* __restrict__ ctrl,
                                                const float* __restrict__ pcoef,
                                                unsigned short* __restrict__ yb) {
  __shared__ __align__(16) char lds[65536];
  const int bid  = blockIdx.x;
  TILE_MAP();
  if (tile >= ctrl[32]) return;
  int e = 7;
  #pragma unroll
  for (int k = 7; k >= 1; --k) if (tile < ctrl[24 + k]) e = k - 1;
  const int rb   = tile - ctrl[24 + e];
  const int Ne   = ctrl[e];
  const int base = ctrl[8 + e];
  const int row0 = rb * 256;
  const int n0   = cb * 256;
  const int tid  = threadIdx.x;
  const int wid  = tid >> 6;
  const int lane = tid & 63;
  const int wr   = wid >> 2;
  const int wc   = wid & 3;
  const int l15  = lane & 15;
  const int l16  = lane >> 4;
  const int NT   = IDIM / 32;   // 32

  const unsigned short *gA0, *gA1, *gB0, *gB1;
  {
    int rl = wid * 16 + (lane >> 2);
    int r0 = rl, r1 = 128 + rl;
    int c80 = (lane & 3) ^ ((r0 >> 1) & 3);
    int c81 = (lane & 3) ^ ((r1 >> 1) & 3);
    int rr0 = row0 + r0; if (rr0 > Ne - 1) rr0 = Ne - 1;
    int rr1 = row0 + r1; if (rr1 > Ne - 1) rr1 = Ne - 1;
    gA0 = actb + (size_t)(base + rr0) * IDIM + c80 * 8;
    gA1 = actb + (size_t)(base + rr1) * IDIM + c81 * 8;
    gB0 = w2b + ((size_t)e * HDIM + n0 + r0) * IDIM + c80 * 8;
    gB1 = w2b + ((size_t)e * HDIM + n0 + r1) * IDIM + c81 * 8;
  }

  f32x4 acc[2][2][4][2];
  #pragma unroll
  for (int qm = 0; qm < 2; ++qm)
    #pragma unroll
    for (int qn = 0; qn < 2; ++qn)
      #pragma unroll
      for (int mi = 0; mi < 4; ++mi)
        #pragma unroll
        for (int ni = 0; ni < 2; ++ni) acc[qm][qn][mi][ni] = (f32x4)(0.0f);

  auto STAGE = [&](int kt) {
    char* d = lds + (kt & 1) * 32768 + wid * 1024;
    GLOAD_LDS16(gA0 + kt * 32, d);
    GLOAD_LDS16(gA1 + kt * 32, d + 8192);
    GLOAD_LDS16(gB0 + kt * 32, d + 16384);
    GLOAD_LDS16(gB1 + kt * 32, d + 24576);
  };

  bf16x8 A0a[4], A1a[4], B0a[2], B1a[2];
  bf16x8 A0b[4], A1b[4], B0b[2], B1b[2];

  STAGE(0); STAGE(1);
  VM_WAITN(4);
  __builtin_amdgcn_s_barrier();
  SBAR0();
  RD_SET(lds, A0a, A1a, B0a, B1a);
  SBAR0();

  for (int i = 0; i < NT; i += 2) {
    ITER(i,     A0a, A1a, B0a, B1a, A0b, A1b, B0b, B1b);
    ITER(i + 1, A0b, A1b, B0b, B1b, A0a, A1a, B0a, B1a);
  }

  // epilogue: contiguous bf16 stores at sorted position, scaled by router coef
  #pragma unroll
  for (int qm = 0; qm < 2; ++qm)
    #pragma unroll
    for (int mi = 0; mi < 4; ++mi)
      #pragma unroll
      for (int jj = 0; jj < 4; ++jj) {
        int r = wr * 128 + qm * 64 + mi * 16 + l16 * 4 + jj;
        int rr = row0 + r;
        if (rr < Ne) {
          float cf = pcoef[base + rr];
          #pragma unroll
          for (int qn = 0; qn < 2; ++qn)
            #pragma unroll
            for (int ni = 0; ni < 2; ++ni) {
              int col = n0 + wc * 64 + qn * 32 + ni * 16 + l15;
              yb[(size_t)(base + rr) * HDIM + col] = f2bf(acc[qm][qn][mi][ni][jj] * cf);
            }
        }
      }
}

// ---------------- reduce: out[t] = yb[pinv[2t]] + yb[pinv[2t+1]] ----------------
__global__ __launch_bounds__(256) void reduce2(const unsigned short* __restrict__ yb,
                                               const int* __restrict__ pinv,
                                               float* __restrict__ out) {
  int i = blockIdx.x * 256 + threadIdx.x;
  int t = i >> 8;                                   // 256 thread-groups of 8 cols
  int g = i & 255;
  int p0 = pinv[2 * t], p1 = pinv[2 * t + 1];
  u16x8 a = *((const u16x8*)(yb + (size_t)p0 * HDIM) + g);
  u16x8 b = *((const u16x8*)(yb + (size_t)p1 * HDIM) + g);
  float4 o0, o1;
  o0.x = bf2f(a[0]) + bf2f(b[0]); o0.y = bf2f(a[1]) + bf2f(b[1]);
  o0.z = bf2f(a[2]) + bf2f(b[2]); o0.w = bf2f(a[3]) + bf2f(b[3]);
  o1.x = bf2f(a[4]) + bf2f(b[4]); o1.y = bf2f(a[5]) + bf2f(b[5]);
  o1.z = bf2f(a[6]) + bf2f(b[6]); o1.w = bf2f(a[7]) + bf2f(b[7]);
  float4* dst = (float4*)(out + (size_t)t * HDIM) + g * 2;
  dst[0] = o0; dst[1] = o1;
}

// ---------------- launcher ----------------
extern "C" void kernel_launch(void* const* d_in, const int* in_sizes, int n_in,
                              void* d_out, int out_size, void* d_ws, size_t ws_size,
                              hipStream_t stream) {
  const float* x   = (const float*)d_in[0];
  const int*   ert = (const int*)d_in[1];
  const float* rw  = (const float*)d_in[2];
  const float* w13 = (const float*)d_in[3];
  const float* w2  = (const float*)d_in[4];
  float* out = (float*)d_out;

  char* ws = (char*)d_ws;
  size_t off = 0;
  auto alloc = [&](size_t bytes) { char* p = ws + off; off += (bytes + 255) & ~255ULL; return p; };
  int*            ctrl  = (int*)           alloc(256);
  int*            porig = (int*)           alloc((size_t)NPAIR * 4);
  float*          pcoef = (float*)         alloc((size_t)NPAIR * 4);
  int*            pinv  = (int*)           alloc((size_t)NPAIR * 4);
  unsigned short* w2b   = (unsigned short*)alloc((size_t)NEXP * HDIM * IDIM * 2);
  unsigned short* actb  = (unsigned short*)alloc((size_t)NPAIR * IDIM * 2);
  unsigned short* w13b  = (unsigned short*)alloc((size_t)NEXP * 2 * IDIM * HDIM * 2);
  unsigned short* xb    = (unsigned short*)alloc((size_t)TOKS * HDIM * 2);
  // yb (NPAIR x HDIM bf16 = 128 MiB) overlays w13b (dead after gemm1)
  unsigned short* yb    = w13b;

  hipMemsetAsync(ctrl, 0, 256, stream);

  cvt_all<<<(W13_N8 + W2_N8 + X_N8) / 256, 256, 0, stream>>>(w13, w2, x, w13b, w2b, xb);

  route_count  <<<NPAIR / 256, 256, 0, stream>>>(ert, ctrl);
  route_scan   <<<1, 64, 0, stream>>>(ctrl);
  route_scatter<<<NPAIR / 256, 256, 0, stream>>>(ert, rw, ctrl, porig, pcoef, pinv);

  gemm1<<<136 * 8, 512, 0, stream>>>(xb, w13b, ctrl, porig, actb);
  gemm2<<<136 * 8, 512, 0, stream>>>(actb, w2b, ctrl, pcoef, yb);
  reduce2<<<(TOKS * HDIM / 8) / 256, 256, 0, stream>>>(yb, pinv, out);
}

// Round 12
// 847.537 us; speedup vs baseline: 9.1603x; 1.0190x over previous
//
#include <hip/hip_runtime.h>
#include <hip/hip_bf16.h>
#include <stdint.h>

#define TOKS 16384
#define HDIM 2048
#define IDIM 1024
#define NEXP 8
#define TOPK 2
#define NPAIR (TOKS*TOPK)   // 32768

typedef __attribute__((ext_vector_type(4))) float f32x4;
typedef __attribute__((ext_vector_type(8))) __bf16 bf16x8;
typedef __attribute__((ext_vector_type(8))) unsigned short u16x8;

#define GLOAD_LDS16(gp, lp) \
  __builtin_amdgcn_global_load_lds((const __attribute__((address_space(1))) void*)(gp), \
                                   (__attribute__((address_space(3))) void*)(lp), 16, 0, 0)

#define LGKM_WAITN(n) asm volatile("s_waitcnt lgkmcnt(" #n ")" ::: "memory")
#define VM_WAITN(n)   asm volatile("s_waitcnt vmcnt(" #n ")" ::: "memory")
#define SBAR0()       __builtin_amdgcn_sched_barrier(0)

__device__ __forceinline__ unsigned short f2bf(float f) {
  unsigned int u = __float_as_uint(f);
  u += 0x7FFF + ((u >> 16) & 1);   // RNE
  return (unsigned short)(u >> 16);
}
__device__ __forceinline__ float bf2f(unsigned short h) {
  return __uint_as_float(((unsigned int)h) << 16);
}

// ---------------- fused conversion: f32 -> bf16 for w13, w2, x ----------------
#define W13_N8 (NEXP * 2 * IDIM * HDIM / 8)   // 4194304
#define W2_N8  (NEXP * HDIM * IDIM / 8)       // 2097152
#define X_N8   (TOKS * HDIM / 8)              // 4194304
__global__ __launch_bounds__(256) void cvt_all(const float* __restrict__ w13,
                                               const float* __restrict__ w2,
                                               const float* __restrict__ x,
                                               unsigned short* __restrict__ w13b,
                                               unsigned short* __restrict__ w2b,
                                               unsigned short* __restrict__ xb) {
  int i = blockIdx.x * 256 + threadIdx.x;
  const float* s; unsigned short* d; int j;
  if (i < W13_N8)              { s = w13; d = w13b; j = i; }
  else if (i < W13_N8 + W2_N8) { s = w2;  d = w2b;  j = i - W13_N8; }
  else                         { s = x;   d = xb;   j = i - W13_N8 - W2_N8; }
  const float4* sp = (const float4*)s + (size_t)j * 2;
  float4 a = sp[0], b = sp[1];
  u16x8 o;
  o[0] = f2bf(a.x); o[1] = f2bf(a.y); o[2] = f2bf(a.z); o[3] = f2bf(a.w);
  o[4] = f2bf(b.x); o[5] = f2bf(b.y); o[6] = f2bf(b.z); o[7] = f2bf(b.w);
  *((u16x8*)d + j) = o;
}

// ---------------- routing ----------------
// ctrl ints: [0..7]=counts [8..15]=offsets [16..23]=cursors [24..31]=rowtile prefix [32]=total tiles
__global__ void route_count(const int* __restrict__ ert, int* __restrict__ ctrl) {
  int p = blockIdx.x * 256 + threadIdx.x;
  if (p < NPAIR) atomicAdd(&ctrl[ert[p]], 1);
}

__global__ void route_scan(int* __restrict__ ctrl) {
  if (blockIdx.x == 0 && threadIdx.x == 0) {
    int off = 0;
    for (int e = 0; e < NEXP; ++e) { ctrl[8 + e] = off; ctrl[16 + e] = off; off += ctrl[e]; }
    int toff = 0;
    for (int e = 0; e < NEXP; ++e) { ctrl[24 + e] = toff; toff += (ctrl[e] + 255) >> 8; }
    ctrl[32] = toff;
  }
}

__global__ void route_scatter(const int* __restrict__ ert, const float* __restrict__ rw,
                              int* __restrict__ ctrl, int* __restrict__ porig,
                              float* __restrict__ pcoef, int* __restrict__ pinv) {
  int p = blockIdx.x * 256 + threadIdx.x;
  if (p < NPAIR) {
    int e = ert[p];
    int pos = atomicAdd(&ctrl[16 + e], 1);
    porig[pos] = p;
    pcoef[pos] = rw[p];
    pinv[p]    = pos;
  }
}

// ===== GEMM machinery: 256x128 block tile, per-wave 64x64 (acc = 64 AGPR),
// BK=32, ring-2 LDS (48 KB), minimal 2-phase schedule. Small register
// footprint (~124 unified regs) -> 4 waves/SIMD -> 2 blocks/CU; overlap of
// MFMA and LDS pipes comes from the co-resident independent block (m114),
// not intra-block scheduling (which rounds 7-11 showed can't break lockstep).
// LDS buf k @ (k&1)*24576: A 256x32 bf16 (16 KB), B 128x32 (8 KB @ +16384).
// Row = 64B = 4x16B slots, slot XOR (row>>1)&3, source pre-swizzled.

#define RD8(lb) do {                                                                 \
  _Pragma("unroll") for (int mi = 0; mi < 4; ++mi) {                                 \
    int r_ = wr * 64 + mi * 16 + l15;                                                \
    fA[mi] = *(const bf16x8*)((lb) + r_ * 64 + ((l16 ^ ((r_ >> 1) & 3)) << 4)); }    \
  _Pragma("unroll") for (int ni = 0; ni < 4; ++ni) {                                 \
    int nb_ = wc * 64 + ni * 16 + l15;                                               \
    fB[ni] = *(const bf16x8*)((lb) + 16384 + nb_ * 64 + ((l16 ^ ((nb_ >> 1) & 3)) << 4)); } \
} while (0)

#define MFMA16() do {                                                                \
  __builtin_amdgcn_s_setprio(1);                                                     \
  _Pragma("unroll") for (int mi = 0; mi < 4; ++mi)                                   \
    _Pragma("unroll") for (int ni = 0; ni < 4; ++ni)                                 \
      acc[mi][ni] = __builtin_amdgcn_mfma_f32_16x16x32_bf16(                         \
          fA[mi], fB[ni], acc[mi][ni], 0, 0, 0);                                     \
  __builtin_amdgcn_s_setprio(0);                                                     \
} while (0)

// Minimal 2-phase iter (guide T3 recipe): STAGE(i+1) -> RD8(buf i) ->
// lgkm(0) -> MFMA -> vmcnt(0) -> barrier.  Race audit: STAGE(i+1) writes
// buf^1 whose iter-(i-1) reads retired before that iter's lgkm(0) and are
// ordered by its end barrier; vm(0)+barrier at end makes tile i+1's writes
// visible to all waves before iter i+1 reads them.
#define GEMM_LOOP() do {                                                             \
  STAGE(0);                                                                          \
  VM_WAITN(0);                                                                       \
  __builtin_amdgcn_s_barrier();                                                      \
  for (int i = 0; i < NT; ++i) {                                                     \
    if (i + 1 < NT) STAGE(i + 1);                                                    \
    const char* lb_ = lds + (i & 1) * 24576;                                         \
    RD8(lb_);                                                                        \
    LGKM_WAITN(0); SBAR0();                                                          \
    MFMA16();                                                                        \
    if (i + 1 < NT) {                                                                \
      VM_WAITN(0);                                                                   \
      __builtin_amdgcn_s_barrier();                                                  \
    }                                                                                \
  }                                                                                  \
} while (0)

// XCD-co-located block map (16 col-blocks per tile on one XCD):
// bid = x + 8*k; cb = k&15; tile = (k>>4)*8 + x.
#define TILE_MAP16()                                                                 \
  const int x_ = bid & 7, k_ = bid >> 3;                                             \
  const int cb = k_ & 15;                                                            \
  const int tile = ((k_ >> 4) << 3) + x_;

// ============ GEMM1: act = silu(x@Wg^T)*(x@Wu^T) ============
// block tile 256 pair-rows x 128 B-rows = 64 act cols; per-wave 64 rows x
// (32 gate + 32 up cols, interleaved as ni 0,1=gate / 2,3=up).
__global__ __launch_bounds__(512, 2) void gemm1(const unsigned short* __restrict__ xb,
                                                const unsigned short* __restrict__ w13b,
                                                const int* __restrict__ ctrl,
                                                const int* __restrict__ porig,
                                                unsigned short* __restrict__ actb) {
  __shared__ __align__(16) char lds[49152];
  const int bid  = blockIdx.x;
  TILE_MAP16();
  if (tile >= ctrl[32]) return;
  int e = 7;
  #pragma unroll
  for (int k = 7; k >= 1; --k) if (tile < ctrl[24 + k]) e = k - 1;
  const int Ne   = ctrl[e];
  const int base = ctrl[8 + e];
  const int row0 = (tile - ctrl[24 + e]) * 256;
  const int c0   = cb * 64;           // act col base (64 cols/block)
  const int tid  = threadIdx.x;
  const int wid  = tid >> 6;
  const int lane = tid & 63;
  const int wr   = wid >> 1;          // 0..3 (64-row slices)
  const int wc   = wid & 1;           // 0..1 (64 B-row slices)
  const int l15  = lane & 15;
  const int l16  = lane >> 4;
  const int NT   = HDIM / 32;         // 64

  // staging pointers (source pre-swizzled). Per gload: row = wid*16 + (lane>>2).
  const unsigned short *gA0, *gA1, *gB0;
  {
    int rl = wid * 16 + (lane >> 2);
    int r0 = rl, r1 = 128 + rl;       // A rows
    int c80 = (lane & 3) ^ ((r0 >> 1) & 3);
    int c81 = (lane & 3) ^ ((r1 >> 1) & 3);
    int rr0 = row0 + r0; if (rr0 > Ne - 1) rr0 = Ne - 1;
    int rr1 = row0 + r1; if (rr1 > Ne - 1) rr1 = Ne - 1;
    gA0 = xb + (size_t)(porig[base + rr0] >> 1) * HDIM + c80 * 8;
    gA1 = xb + (size_t)(porig[base + rr1] >> 1) * HDIM + c81 * 8;
    // B row rl (0..127): n = rl&63; half n>>5 -> up (w13 row IDIM+col);
    // col = c0 + (rl>>6)*32 + (n&31)   [rl>>6 == wc of the consuming wave]
    int n  = rl & 63;
    int gr = ((n & 32) ? IDIM : 0) + c0 + ((rl >> 6) << 5) + (n & 31);
    gB0 = w13b + ((size_t)e * (2 * IDIM) + gr) * HDIM + c80 * 8;
  }

  f32x4 acc[4][4];
  #pragma unroll
  for (int mi = 0; mi < 4; ++mi)
    #pragma unroll
    for (int ni = 0; ni < 4; ++ni) acc[mi][ni] = (f32x4)(0.0f);

  auto STAGE = [&](int kt) {
    char* d = lds + (kt & 1) * 24576 + wid * 1024;
    GLOAD_LDS16(gA0 + kt * 32, d);
    GLOAD_LDS16(gA1 + kt * 32, d + 8192);
    GLOAD_LDS16(gB0 + kt * 32, d + 16384);
  };

  bf16x8 fA[4], fB[4];
  GEMM_LOOP();

  // epilogue: silu(gate)*up -> bf16 act  (ni 0,1 = gate; ni+2 = up, same cols)
  #pragma unroll
  for (int mi = 0; mi < 4; ++mi)
    #pragma unroll
    for (int jj = 0; jj < 4; ++jj) {
      int r  = wr * 64 + mi * 16 + l16 * 4 + jj;
      int rr = row0 + r;
      if (rr < Ne) {
        #pragma unroll
        for (int ni = 0; ni < 2; ++ni) {
          float g = acc[mi][ni][jj];
          float u = acc[mi][ni + 2][jj];
          float a = g / (1.0f + __expf(-g)) * u;
          actb[(size_t)(base + rr) * IDIM + (c0 + wc * 32 + ni * 16 + l15)] = f2bf(a);
        }
      }
    }
}

// ============ GEMM2: yb[pos] = coef * (act @ w2^T) ============
// block tile 256 pair-rows x 128 out cols.
__global__ __launch_bounds__(512, 2) void gemm2(const unsigned short* __restrict__ actb,
                                                const unsigned short* __restrict__ w2b,
                                                const int* __restrict__ ctrl,
                                                const float* __restrict__ pcoef,
                                                unsigned short* __restrict__ yb) {
  __shared__ __align__(16) char lds[49152];
  const int bid  = blockIdx.x;
  TILE_MAP16();
  if (tile >= ctrl[32]) return;
  int e = 7;
  #pragma unroll
  for (int k = 7; k >= 1; --k) if (tile < ctrl[24 + k]) e = k - 1;
  const int Ne   = ctrl[e];
  const int base = ctrl[8 + e];
  const int row0 = (tile - ctrl[24 + e]) * 256;
  const int n0   = cb * 128;          // out col base
  const int tid  = threadIdx.x;
  const int wid  = tid >> 6;
  const int lane = tid & 63;
  const int wr   = wid >> 1;
  const int wc   = wid & 1;
  const int l15  = lane & 15;
  const int l16  = lane >> 4;
  const int NT   = IDIM / 32;         // 32

  const unsigned short *gA0, *gA1, *gB0;
  {
    int rl = wid * 16 + (lane >> 2);
    int r0 = rl, r1 = 128 + rl;
    int c80 = (lane & 3) ^ ((r0 >> 1) & 3);
    int c81 = (lane & 3) ^ ((r1 >> 1) & 3);
    int rr0 = row0 + r0; if (rr0 > Ne - 1) rr0 = Ne - 1;
    int rr1 = row0 + r1; if (rr1 > Ne - 1) rr1 = Ne - 1;
    gA0 = actb + (size_t)(base + rr0) * IDIM + c80 * 8;
    gA1 = actb + (size_t)(base + rr1) * IDIM + c81 * 8;
    gB0 = w2b + ((size_t)e * HDIM + n0 + rl) * IDIM + c80 * 8;
  }

  f32x4 acc[4][4];
  #pragma unroll
  for (int mi = 0; mi < 4; ++mi)
    #pragma unroll
    for (int ni = 0; ni < 4; ++ni) acc[mi][ni] = (f32x4)(0.0f);

  auto STAGE = [&](int kt) {
    char* d = lds + (kt & 1) * 24576 + wid * 1024;
    GLOAD_LDS16(gA0 + kt * 32, d);
    GLOAD_LDS16(gA1 + kt * 32, d + 8192);
    GLOAD_LDS16(gB0 + kt * 32, d + 16384);
  };

  bf16x8 fA[4], fB[4];
  GEMM_LOOP();

  // epilogue: contiguous bf16 stores at sorted position, scaled by router coef
  #pragma unroll
  for (int mi = 0; mi < 4; ++mi)
    #pragma unroll
    for (int jj = 0; jj < 4; ++jj) {
      int r  = wr * 64 + mi * 16 + l16 * 4 + jj;
      int rr = row0 + r;
      if (rr < Ne) {
        float cf = pcoef[base + rr];
        #pragma unroll
        for (int ni = 0; ni < 4; ++ni) {
          int col = n0 + wc * 64 + ni * 16 + l15;
          yb[(size_t)(base + rr) * HDIM + col] = f2bf(acc[mi][ni][jj] * cf);
        }
      }
    }
}

// ---------------- reduce: out[t] = yb[pinv[2t]] + yb[pinv[2t+1]] ----------------
__global__ __launch_bounds__(256) void reduce2(const unsigned short* __restrict__ yb,
                                               const int* __restrict__ pinv,
                                               float* __restrict__ out) {
  int i = blockIdx.x * 256 + threadIdx.x;
  int t = i >> 8;                                   // 256 thread-groups of 8 cols
  int g = i & 255;
  int p0 = pinv[2 * t], p1 = pinv[2 * t + 1];
  u16x8 a = *((const u16x8*)(yb + (size_t)p0 * HDIM) + g);
  u16x8 b = *((const u16x8*)(yb + (size_t)p1 * HDIM) + g);
  float4 o0, o1;
  o0.x = bf2f(a[0]) + bf2f(b[0]); o0.y = bf2f(a[1]) + bf2f(b[1]);
  o0.z = bf2f(a[2]) + bf2f(b[2]); o0.w = bf2f(a[3]) + bf2f(b[3]);
  o1.x = bf2f(a[4]) + bf2f(b[4]); o1.y = bf2f(a[5]) + bf2f(b[5]);
  o1.z = bf2f(a[6]) + bf2f(b[6]); o1.w = bf2f(a[7]) + bf2f(b[7]);
  float4* dst = (float4*)(out + (size_t)t * HDIM) + g * 2;
  dst[0] = o0; dst[1] = o1;
}

// ---------------- launcher ----------------
extern "C" void kernel_launch(void* const* d_in, const int* in_sizes, int n_in,
                              void* d_out, int out_size, void* d_ws, size_t ws_size,
                              hipStream_t stream) {
  const float* x   = (const float*)d_in[0];
  const int*   ert = (const int*)d_in[1];
  const float* rw  = (const float*)d_in[2];
  const float* w13 = (const float*)d_in[3];
  const float* w2  = (const float*)d_in[4];
  float* out = (float*)d_out;

  char* ws = (char*)d_ws;
  size_t off = 0;
  auto alloc = [&](size_t bytes) { char* p = ws + off; off += (bytes + 255) & ~255ULL; return p; };
  int*            ctrl  = (int*)           alloc(256);
  int*            porig = (int*)           alloc((size_t)NPAIR * 4);
  float*          pcoef = (float*)         alloc((size_t)NPAIR * 4);
  int*            pinv  = (int*)           alloc((size_t)NPAIR * 4);
  unsigned short* w2b   = (unsigned short*)alloc((size_t)NEXP * HDIM * IDIM * 2);
  unsigned short* actb  = (unsigned short*)alloc((size_t)NPAIR * IDIM * 2);
  unsigned short* w13b  = (unsigned short*)alloc((size_t)NEXP * 2 * IDIM * HDIM * 2);
  unsigned short* xb    = (unsigned short*)alloc((size_t)TOKS * HDIM * 2);
  // yb (NPAIR x HDIM bf16 = 128 MiB) overlays w13b (dead after gemm1)
  unsigned short* yb    = w13b;

  hipMemsetAsync(ctrl, 0, 256, stream);

  cvt_all<<<(W13_N8 + W2_N8 + X_N8) / 256, 256, 0, stream>>>(w13, w2, x, w13b, w2b, xb);

  route_count  <<<NPAIR / 256, 256, 0, stream>>>(ert, ctrl);
  route_scan   <<<1, 64, 0, stream>>>(ctrl);
  route_scatter<<<NPAIR / 256, 256, 0, stream>>>(ert, rw, ctrl, porig, pcoef, pinv);

  // grid: 8 XCD-slots x 16 col-blocks x ceil(136/8) tile-groups = 2176
  gemm1<<<2176, 512, 0, stream>>>(xb, w13b, ctrl, porig, actb);
  gemm2<<<2176, 512, 0, stream>>>(actb, w2b, ctrl, pcoef, yb);
  reduce2<<<(TOKS * HDIM / 8) / 256, 256, 0, stream>>>(yb, pinv, out);
}